// Round 12
// baseline (61.765 us; speedup 1.0000x reference)
//
#include <hip/hip_runtime.h>

// Problem constants (fixed by the reference)
#define BATCH   8192
#define GROUPS  512
#define ARITY   3
#define OUT_DIM 16
#define NV      27          // 3^3 vertices
#define XCOLS   (GROUPS*ARITY)      // 1536
#define OCOLS   (GROUPS*OUT_DIM)    // 8192

// R12: barrier-free streaming. vs R11 (60.0us):
//  - X read DIRECTLY from global per lane (12B triple; 4 oq-lanes dup-read,
//    coalescer dedups to a 192B/row wave segment; HBM X traffic unchanged).
//  - deletes per-chunk vmcnt(0)+barrier pairs (8 block-wide ~900cy stalls),
//    all X staging code, 3 ds_reads/iter, the NCHUNK machinery.
//  - single barrier total (after params staging). Pure stream loop.
// Wave wv owns rows bbase+wv+4i -> block write front = 4 consecutive rows.
// LDS = params only 14208B; grid (32 g-fast x 64) = 2048 blocks = 8/CU.
#define GTILE 16
#define BROWS 128       // rows per block
#define PSTRIDE 444     // bf16 elems per group (432 + 12 pad)

typedef float    f32x4 __attribute__((ext_vector_type(4)));
typedef unsigned u32x2 __attribute__((ext_vector_type(2)));

__device__ __forceinline__ unsigned cvt_pk_bf16(float lo, float hi) {
    unsigned r;
    asm("v_cvt_pk_bf16_f32 %0, %1, %2" : "=v"(r) : "v"(lo), "v"(hi));
    return r;
}
__device__ __forceinline__ float bflo(unsigned u) {
    union { unsigned u; float f; } c; c.u = u << 16; return c.f;
}
__device__ __forceinline__ float bfhi(unsigned u) {
    union { unsigned u; float f; } c; c.u = u & 0xffff0000u; return c.f;
}

__global__ __launch_bounds__(256, 8) void lattice_interp_kernel(
    const float* __restrict__ X,
    const float* __restrict__ P,
    float* __restrict__ out)
{
    __shared__ unsigned short ps[GTILE * PSTRIDE];     // 7104 bf16 = 14208 B

    const int t  = threadIdx.x;
    const int g0 = blockIdx.x * GTILE;        // group chunk: FAST grid dim
    const int bbase = blockIdx.y * BROWS;     // 128-row span: SLOW grid dim

    // ---- stage params for 16 groups as bf16 (once per block):
    // 1728 float4 -> cvt_pk -> ds_write_b64. group pgl at elem pgl*444.
    {
        const float4* src = reinterpret_cast<const float4*>(P + (size_t)g0 * (NV * OUT_DIM));
        #pragma unroll
        for (int k = 0; k < 7; ++k) {
            const int f = t + k * 256;
            if (f < 1728) {
                const float4 v = src[f];
                const int pgl = f / 108;          // 108 float4 per group
                const int rem = f - pgl * 108;
                u32x2 w;
                w.x = cvt_pk_bf16(v.x, v.y);
                w.y = cvt_pk_bf16(v.z, v.w);
                *reinterpret_cast<u32x2*>(&ps[pgl * PSTRIDE + rem * 4]) = w;
            }
        }
    }

    __syncthreads();   // the ONLY barrier

    const int wv = t >> 6;
    const int l  = t & 63;
    const int gl = l >> 2;    // group-local 0..15
    const int oq = l & 3;     // which float4 of the 16 outputs

    const unsigned short* pbase = ps + gl * PSTRIDE + oq * 4;  // + vb*16 at runtime

    // wave wv handles rows bbase + wv + 4*i, i = 0..31
    const float* xrow = X + (size_t)(bbase + wv) * XCOLS + (size_t)(g0 + gl) * ARITY;
    float* outp = out + (size_t)(bbase + wv) * OCOLS + (size_t)g0 * OUT_DIM + l * 4;

    // 1-deep x prefetch; TLP (8 waves/SIMD) covers the rest of the latency
    float x0 = xrow[0], x1 = xrow[1], x2 = xrow[2];

    #pragma unroll 2
    for (int i = 0; i < BROWS / 4; ++i) {
        const float cx0 = x0, cx1 = x1, cx2 = x2;
        if (i + 1 < BROWS / 4) {
            const float* nx = xrow + (size_t)(i + 1) * 4 * XCOLS;
            x0 = nx[0]; x1 = nx[1]; x2 = nx[2];
        }

        // containing cell per dim; lower/upper hat weights (3rd weight == 0)
        const bool n0 = cx0 < 0.0f, n1 = cx1 < 0.0f, n2 = cx2 < 0.0f;
        const float wl0 = n0 ? -cx0       : 1.0f - cx0;
        const float wh0 = n0 ? 1.0f + cx0 : cx0;
        const float wl1 = n1 ? -cx1       : 1.0f - cx1;
        const float wh1 = n1 ? 1.0f + cx1 : cx1;
        const float wl2 = n2 ? -cx2       : 1.0f - cx2;
        const float wh2 = n2 ? 1.0f + cx2 : cx2;
        const int   vb  = (n0 ? 0 : 1) + 3 * (n1 ? 0 : 1) + 9 * (n2 ? 0 : 1);

        // 8 corner weights
        const float wA = wl0 * wl1, wB = wh0 * wl1, wC = wl0 * wh1, wD = wh0 * wh1;
        const float c000 = wA * wl2, c100 = wB * wl2, c010 = wC * wl2, c110 = wD * wl2;
        const float c001 = wA * wh2, c101 = wB * wh2, c011 = wC * wh2, c111 = wD * wh2;

        // one runtime base + 8 immediate-offset ds_read_b64 (4 bf16 each);
        // offsets pair up (0,4)(12,16)(36,40)(48,52) -> ds_read2_b64 fusable
        const u32x2* pp = reinterpret_cast<const u32x2*>(pbase + (size_t)vb * 16);
        const u32x2 r0 = pp[0];        // dv=0  (c000)
        const u32x2 r1 = pp[4];        // dv=1  (c100)
        const u32x2 r2 = pp[12];       // dv=3  (c010)
        const u32x2 r3 = pp[16];       // dv=4  (c110)
        const u32x2 r4 = pp[36];       // dv=9  (c001)
        const u32x2 r5 = pp[40];       // dv=10 (c101)
        const u32x2 r6 = pp[48];       // dv=12 (c011)
        const u32x2 r7 = pp[52];       // dv=13 (c111)

        f32x4 acc;
        { f32x4 pv = { bflo(r0.x), bfhi(r0.x), bflo(r0.y), bfhi(r0.y) }; acc  = c000 * pv; }
        { f32x4 pv = { bflo(r1.x), bfhi(r1.x), bflo(r1.y), bfhi(r1.y) }; acc += c100 * pv; }
        { f32x4 pv = { bflo(r2.x), bfhi(r2.x), bflo(r2.y), bfhi(r2.y) }; acc += c010 * pv; }
        { f32x4 pv = { bflo(r3.x), bfhi(r3.x), bflo(r3.y), bfhi(r3.y) }; acc += c110 * pv; }
        { f32x4 pv = { bflo(r4.x), bfhi(r4.x), bflo(r4.y), bfhi(r4.y) }; acc += c001 * pv; }
        { f32x4 pv = { bflo(r5.x), bfhi(r5.x), bflo(r5.y), bfhi(r5.y) }; acc += c101 * pv; }
        { f32x4 pv = { bflo(r6.x), bfhi(r6.x), bflo(r6.y), bfhi(r6.y) }; acc += c011 * pv; }
        { f32x4 pv = { bflo(r7.x), bfhi(r7.x), bflo(r7.y), bfhi(r7.y) }; acc += c111 * pv; }

        __builtin_nontemporal_store(acc,
            reinterpret_cast<f32x4*>(outp + (size_t)i * 4 * OCOLS));
    }
}

extern "C" void kernel_launch(void* const* d_in, const int* in_sizes, int n_in,
                              void* d_out, int out_size, void* d_ws, size_t ws_size,
                              hipStream_t stream) {
    const float* X = (const float*)d_in[0];   // [8192, 1536] f32
    const float* P = (const float*)d_in[1];   // [512, 27, 16] f32
    float* out = (float*)d_out;               // [8192, 8192] f32

    dim3 grid(GROUPS / GTILE, BATCH / BROWS); // 32 x 64 = 2048 (g fast)
    dim3 block(256);
    lattice_interp_kernel<<<grid, block, 0, stream>>>(X, P, out);
}